// Round 1
// 128.685 us; speedup vs baseline: 1.0147x; 1.0147x over previous
//
#include <hip/hip_runtime.h>
#include <hip/hip_bf16.h>
#include <stdint.h>

#define NN 4096      // nodes
#define KD 512       // input dim of both GEMMs (512 = IN_DIM = HID*HEADS)

typedef __attribute__((ext_vector_type(8))) short short8;
typedef __attribute__((ext_vector_type(4))) float f32x4;

__device__ __forceinline__ float lrelu(float x) { return fmaxf(x, 0.2f * x); }

__device__ __forceinline__ unsigned short f2bf(float f) {
    uint32_t u = __float_as_uint(f);
    u += 0x7fff + ((u >> 16) & 1);           // RNE
    return (unsigned short)(u >> 16);
}

// async global->LDS, 16B per lane; lds ptr must be wave-uniform base
__device__ __forceinline__ void glds16(const void* g, void* l) {
    __builtin_amdgcn_global_load_lds(
        (const __attribute__((address_space(1))) uint32_t*)g,
        (__attribute__((address_space(3))) uint32_t*)l, 16, 0, 0);
}

// ---------------- bitmask: g[N][N] int32 -> bm[N][64] uint64 ----------------
__global__ void k_bitmask(const int* __restrict__ g, uint64_t* __restrict__ bm) {
    int wave = threadIdx.x >> 6;
    int lane = threadIdx.x & 63;
    int row = blockIdx.x * 4 + wave;
    const int* grow = g + (size_t)row * NN;
    for (int w = 0; w < 64; ++w) {
        int v = grow[w * 64 + lane];
        unsigned long long m = __ballot(v > 0);
        if (lane == 0) bm[(size_t)row * 64 + w] = m;
    }
}

// ---------------- cast f32 -> bf16 (vectorized) ----------------
__global__ void k_cast(const float* __restrict__ x, unsigned short* __restrict__ y, int n4) {
    int i = blockIdx.x * 256 + threadIdx.x;
    if (i < n4) {
        float4 v = ((const float4*)x)[i];
        uint2 o;
        o.x = (uint32_t)f2bf(v.x) | ((uint32_t)f2bf(v.y) << 16);
        o.y = (uint32_t)f2bf(v.z) | ((uint32_t)f2bf(v.w) << 16);
        ((uint2*)y)[i] = o;
    }
}

// ---------------- generic transpose+cast: src f32 [b][R][C] -> dst bf16 [b][C][R] ----------------
__global__ __launch_bounds__(256)
void k_tc(const float* __restrict__ src, unsigned short* __restrict__ dst, int R, int C) {
    __shared__ float tile[64][65];
    int b = blockIdx.z;
    int r0 = blockIdx.x * 64, c0 = blockIdx.y * 64;
    src += (size_t)b * R * C;
    dst += (size_t)b * C * R;
    int t = threadIdx.x;
    #pragma unroll
    for (int s = 0; s < 16; ++s) {
        int idx = t + s * 256;
        int r = idx >> 6, c = idx & 63;
        tile[r][c] = src[(size_t)(r0 + r) * C + c0 + c];
    }
    __syncthreads();
    #pragma unroll
    for (int s = 0; s < 16; ++s) {
        int idx = t + s * 256;
        int r = idx >> 6, c = idx & 63;
        dst[(size_t)(c0 + r) * R + r0 + c] = f2bf(tile[c][r]);
    }
}

// ---------------- fused MFMA GEMM: Wh = A @ W, epilogue writes WhT bf16, s1/s2, smax key ----
// A bf16 [NN][512], WT bf16 [nh][F][512]. BM=32, BK=64, 8 waves (2row x 4col).
template <int F>
__global__ __launch_bounds__(512)
void k_gemm_fused(const unsigned short* __restrict__ Abf, const unsigned short* __restrict__ WT,
                  const float* __restrict__ avec,
                  unsigned short* __restrict__ WhT, float* __restrict__ s1g,
                  float* __restrict__ s2g, unsigned int* __restrict__ smaxKey) {
    constexpr int BM = 32, BK = 64;
    constexpr int NCF = F / 64;
    __shared__ unsigned short a_lds[2][BM * BK];
    __shared__ unsigned short b_lds[2][F * BK];
    __shared__ unsigned short t_lds[F * 40];
    __shared__ float sred[BM][2];
    int t = threadIdx.x, lane = t & 63, w = t >> 6;
    int h = blockIdx.y;
    int i0 = blockIdx.x * BM;
    const unsigned short* WTh = WT + (size_t)h * F * KD;
    int r0 = (w >> 2) * 16, c0 = (w & 3) * (F / 4);
    int krow = lane & 15, kgrp = lane >> 4;
    if (t < BM) { sred[t][0] = 0.f; sred[t][1] = 0.f; }
    f32x4 acc[NCF];
    #pragma unroll
    for (int cf = 0; cf < NCF; ++cf) acc[cf] = (f32x4){0.f, 0.f, 0.f, 0.f};

    auto stage = [&](int buf, int kt) {
        int k0 = kt * BK;
        if (w < 4) {            // A tile: 256 chunks
            int c = w * 64 + lane;
            int row = c >> 3, slot = c & 7;
            glds16(Abf + (size_t)(i0 + row) * KD + k0 + ((slot ^ (row & 7)) * 8),
                   &a_lds[buf][(w * 64) * 8]);
        }
        #pragma unroll
        for (int s = 0; s < F / 64; ++s) {   // B tile: 8F chunks
            int c = w * F + s * 64 + lane;
            int row = c >> 3, slot = c & 7;
            glds16(WTh + (size_t)row * KD + k0 + ((slot ^ (row & 7)) * 8),
                   &b_lds[buf][(w * F + s * 64) * 8]);
        }
    };

    stage(0, 0);
    __syncthreads();
    int cur = 0;
    for (int kt = 0; kt < KD / BK; ++kt) {
        int nxt = cur ^ 1;
        if (kt + 1 < KD / BK) stage(nxt, kt + 1);
        #pragma unroll
        for (int ks = 0; ks < 2; ++ks) {
            int koff = ks * 32 + kgrp * 8;
            int arow = r0 + krow;
            short8 av = *(const short8*)((const char*)&a_lds[cur][arow * BK] +
                                         ((koff * 2) ^ ((arow & 7) << 4)));
            #pragma unroll
            for (int cf = 0; cf < NCF; ++cf) {
                int brow = c0 + cf * 16 + krow;
                short8 bv = *(const short8*)((const char*)&b_lds[cur][brow * BK] +
                                             ((koff * 2) ^ ((brow & 7) << 4)));
                acc[cf] = __builtin_amdgcn_mfma_f32_16x16x32_bf16(av, bv, acc[cf], 0, 0, 0);
            }
        }
        __syncthreads();
        cur = nxt;
    }
    // ---- epilogue ----
    // transpose-store acc to t_lds bf16 + score partials
    float p1[4] = {0.f, 0.f, 0.f, 0.f}, p2[4] = {0.f, 0.f, 0.f, 0.f};
    const float* ah = avec + (size_t)h * 2 * F;
    #pragma unroll
    for (int cf = 0; cf < NCF; ++cf) {
        int col = c0 + cf * 16 + krow;
        float aw1 = ah[col], aw2 = ah[F + col];
        #pragma unroll
        for (int r = 0; r < 4; ++r) {
            int row = r0 + kgrp * 4 + r;
            t_lds[col * 40 + row] = f2bf(acc[cf][r]);
            p1[r] += acc[cf][r] * aw1;
            p2[r] += acc[cf][r] * aw2;
        }
    }
    #pragma unroll
    for (int d = 1; d < 16; d <<= 1) {
        #pragma unroll
        for (int r = 0; r < 4; ++r) { p1[r] += __shfl_xor(p1[r], d); p2[r] += __shfl_xor(p2[r], d); }
    }
    if (krow == 0) {
        #pragma unroll
        for (int r = 0; r < 4; ++r) {
            int row = r0 + kgrp * 4 + r;
            atomicAdd(&sred[row][0], p1[r]);
            atomicAdd(&sred[row][1], p2[r]);
        }
    }
    __syncthreads();
    {
        int col = t >> 2, seg = (t & 3) * 8;
        if (col < F) {
            uint4 v = *(const uint4*)&t_lds[col * 40 + seg];
            *(uint4*)&WhT[((size_t)h * F + col) * NN + i0 + seg] = v;
        }
    }
    if (t < BM) {
        s1g[(size_t)h * NN + i0 + t] = sred[t][0];
        s2g[(size_t)h * NN + i0 + t] = sred[t][1];
    }
    if (w == 0) {
        float v = (t < BM) ? sred[t][1] : -3.4e38f;
        #pragma unroll
        for (int d = 1; d < 64; d <<= 1) v = fmaxf(v, __shfl_xor(v, d));
        if (lane == 0) {
            uint32_t b = __float_as_uint(v);
            uint32_t key = (b & 0x80000000u) ? ~b : (b | 0x80000000u);
            atomicMax(smaxKey + h, key);
        }
    }
}

// ---------------- register-P MFMA masked-softmax aggregation ----------------
// NW waves; NJH = intra-block j-split (waves per row-group). rg = w>>log2(NJH) owns
// 32 rows, jh = w&(NJH-1) owns a K=32 j-quarter of each TJ=NJH*32 tile.
// P computed straight into MFMA A-fragments (no LDS); whT tile tri-buffered, 1 barrier/tile.
template <int F, int NW, int NJH>
__global__ __launch_bounds__(NW * 64, 4)
void k_agg3(const unsigned short* __restrict__ WhT, const float* __restrict__ s1v,
            const float* __restrict__ s2v, const unsigned int* __restrict__ smaxKey,
            const unsigned char* __restrict__ bmb,
            float* __restrict__ pnum, float* __restrict__ pden, int njt, int nh) {
    constexpr int TI = (NW / NJH) * 32, TJ = NJH * 32;
    constexpr int NB = F / 16;           // B frags per wave
    constexpr int CPR = TJ / 8;          // 16B staging chunks per whT row
    constexpr int CH_W = F * CPR / NW;   // 16B staging chunks per wave
    __shared__ unsigned short whT_lds[3][F * TJ];
    __shared__ float den_sh[NJH][TI];
    int t = threadIdx.x, l = t & 63, w = t >> 6;
    int h = blockIdx.y, js = blockIdx.z;
    int i0 = blockIdx.x * TI;
    int rg = w / NJH, jh = w % NJH;
    int r0 = rg * 32;
    const unsigned short* WhTh = WhT + (size_t)h * F * NN;
    const float* s2h = s2v + (size_t)h * NN;
    unsigned int kk = smaxKey[h];
    float smax = __uint_as_float((kk & 0x80000000u) ? (kk ^ 0x80000000u) : ~kk);
    int rowA = i0 + r0 + (l & 15);
    int rowB = rowA + 16;
    float s1A = s1v[(size_t)h * NN + rowA];
    float s1B = s1v[(size_t)h * NN + rowB];
    float miA = lrelu(s1A + smax), miB = lrelu(s1B + smax);
    int joff = jh * 32 + (l >> 4) * 8;
    int jsbase = js * njt;
    const unsigned char* bmbA = bmb + (size_t)rowA * 512;
    const unsigned char* bmbB = bmb + (size_t)rowB * 512;

    f32x4 acc[2][NB];
    #pragma unroll
    for (int m = 0; m < 2; ++m)
        #pragma unroll
        for (int b = 0; b < NB; ++b) acc[m][b] = (f32x4){0.f, 0.f, 0.f, 0.f};
    float denA = 0.f, denB = 0.f;

    struct SD { float4 q0, q1; unsigned int mA, mB; };
    struct PA { short8 a, b; };

    auto loadSD = [&](int jt) {
        SD s;
        int j0 = (jsbase + jt) * TJ;
        s.q0 = *(const float4*)&s2h[j0 + joff];
        s.q1 = *(const float4*)&s2h[j0 + joff + 4];
        int wb = (jsbase + jt) * CPR + jh * 4 + (l >> 4);
        s.mA = bmbA[wb];
        s.mB = bmbB[wb];
        return s;
    };

    auto computeP = [&](const SD& s) {
        float q[8] = {s.q0.x, s.q0.y, s.q0.z, s.q0.w, s.q1.x, s.q1.y, s.q1.z, s.q1.w};
        union { unsigned short u[8]; short8 v; } ua, ub;
        #pragma unroll
        for (int u = 0; u < 8; ++u) {
            float eA = s1A + q[u];
            eA = fmaxf(eA, 0.2f * eA);
            float pA = ((s.mA >> u) & 1u) ? __expf(eA - miA) : 0.f;
            unsigned short hA = f2bf(pA);
            ua.u[u] = hA;
            denA += __uint_as_float((uint32_t)hA << 16);
            float eB = s1B + q[u];
            eB = fmaxf(eB, 0.2f * eB);
            float pB = ((s.mB >> u) & 1u) ? __expf(eB - miB) : 0.f;
            unsigned short hB = f2bf(pB);
            ub.u[u] = hB;
            denB += __uint_as_float((uint32_t)hB << 16);
        }
        PA p; p.a = ua.v; p.b = ub.v;
        return p;
    };

    auto stage = [&](int buf, int jt) {
        int j0 = (jsbase + jt) * TJ;
        #pragma unroll
        for (int s = 0; s < CH_W / 64; ++s) {
            int c = w * CH_W + s * 64 + l;
            int row = c / CPR, slot = c % CPR;
            glds16(WhTh + (size_t)row * NN + j0 + ((slot ^ (row & 7)) * 8),
                   &whT_lds[buf][(w * CH_W + s * 64) * 8]);
        }
    };

    auto domfma = [&](int buf, const PA& pa) {
        #pragma unroll
        for (int b = 0; b < NB; ++b) {
            int brow = b * 16 + (l & 15);
            short8 bv = *(const short8*)((const char*)&whT_lds[buf][brow * TJ] +
                         ((jh * 64 + (l >> 4) * 16) ^ ((brow & 7) << 4)));
            acc[0][b] = __builtin_amdgcn_mfma_f32_16x16x32_bf16(pa.a, bv, acc[0][b], 0, 0, 0);
            acc[1][b] = __builtin_amdgcn_mfma_f32_16x16x32_bf16(pa.b, bv, acc[1][b], 0, 0, 0);
        }
    };

    // prologue
    SD sd_cur = loadSD(0);
    stage(0, 0);
    SD sd_nxt;
    if (njt > 1) sd_nxt = loadSD(1);
    PA pa_cur = computeP(sd_cur);
    __syncthreads();
    int cur = 0, nx1 = 1;
    for (int jt = 0; jt < njt; ++jt) {
        bool more = jt + 1 < njt;
        if (more) stage(nx1, jt + 1);
        SD sd2;
        if (jt + 2 < njt) sd2 = loadSD(jt + 2);
        PA pa_n;
        if (more) pa_n = computeP(sd_nxt);
        __syncthreads();        // tri-buffer: stage target != any in-flight mfma buffer
        domfma(cur, pa_cur);
        pa_cur = pa_n;
        sd_nxt = sd2;
        cur = nx1;
        nx1 = nx1 + 1 == 3 ? 0 : nx1 + 1;
    }

    // den: sum k-groups (lanes sharing l&15)
    denA += __shfl_xor(denA, 16); denA += __shfl_xor(denA, 32);
    denB += __shfl_xor(denB, 16); denB += __shfl_xor(denB, 32);
    if (l < 16) {
        den_sh[jh][r0 + l] = denA;
        den_sh[jh][r0 + 16 + l] = denB;
    }
    __syncthreads();

    // merge jh slices of acc via LDS (two row-passes), write pnum
    constexpr int XROWS = TI / 2;        // rows per m-pass
    float* xch = (float*)whT_lds;        // reuse staging LDS: (NJH-1)*XROWS*F floats
    float* pnumS = pnum + ((size_t)(js * nh + h) * NN + i0) * F;
    #pragma unroll
    for (int m = 0; m < 2; ++m) {
        if (jh > 0) {
            float* sl = xch + (size_t)(jh - 1) * XROWS * F;
            #pragma unroll
            for (int b = 0; b < NB; ++b) {
                int col = b * 16 + (l & 15);
                #pragma unroll
                for (int r = 0; r < 4; ++r)
                    sl[(rg * 16 + (l >> 4) * 4 + r) * F + col] = acc[m][b][r];
            }
        }
        __syncthreads();
        if (jh == 0) {
            #pragma unroll
            for (int b = 0; b < NB; ++b) {
                int col = b * 16 + (l & 15);
                #pragma unroll
                for (int r = 0; r < 4; ++r) {
                    int lrow = rg * 16 + (l >> 4) * 4 + r;
                    int row = r0 + m * 16 + (l >> 4) * 4 + r;
                    float v = acc[m][b][r];
                    #pragma unroll
                    for (int sX = 1; sX < NJH; ++sX)
                        v += xch[((size_t)(sX - 1) * XROWS + lrow) * F + col];
                    pnumS[(size_t)row * F + col] = v;
                }
            }
        }
        __syncthreads();
    }
    if (t < TI) {
        float d = den_sh[0][t];
        #pragma unroll
        for (int sX = 1; sX < NJH; ++sX) d += den_sh[sX][t];
        pden[(size_t)(js * nh + h) * NN + i0 + t] = d;
    }
}

// ---------------- reduce layer-1 partials -> hbuf bf16 (with ELU) ----------------
__global__ void k_reduce1(const float* __restrict__ pnum, const float* __restrict__ pden,
                          unsigned short* __restrict__ hbuf) {
    int idx = blockIdx.x * 256 + threadIdx.x;   // NN*128 float4s
    int i = idx >> 7;
    int c4 = idx & 127;
    int hh = c4 >> 5, f4 = c4 & 31;
    float4 a = *(const float4*)&pnum[((size_t)hh * NN + i) * 128 + f4 * 4];
    float4 b = *(const float4*)&pnum[((size_t)(4 + hh) * NN + i) * 128 + f4 * 4];
    float den = pden[(size_t)hh * NN + i] + pden[(size_t)(4 + hh) * NN + i];
    float inv = 1.f / den;
    float v[4] = {(a.x + b.x) * inv, (a.y + b.y) * inv, (a.z + b.z) * inv, (a.w + b.w) * inv};
    uint2 o;
    unsigned short e[4];
    #pragma unroll
    for (int u = 0; u < 4; ++u) {
        float x = v[u];
        x = x > 0.f ? x : expm1f(x);
        e[u] = f2bf(x);
    }
    o.x = (uint32_t)e[0] | ((uint32_t)e[1] << 16);
    o.y = (uint32_t)e[2] | ((uint32_t)e[3] << 16);
    *(uint2*)&hbuf[(size_t)i * 512 + c4 * 4] = o;
}

// ---------------- reduce layer-2 partials -> out f32 ----------------
__global__ void k_reduce2(const float* __restrict__ pnum, const float* __restrict__ pden,
                          float* __restrict__ out) {
    int idx = blockIdx.x * 256 + threadIdx.x;   // NN*16 float4s
    int i = idx >> 4;
    int f4 = (idx & 15) * 4;
    float4 s = {0.f, 0.f, 0.f, 0.f};
    float den = 0.f;
    #pragma unroll
    for (int js = 0; js < 8; ++js) {
        float4 v = *(const float4*)&pnum[((size_t)js * NN + i) * 64 + f4];
        s.x += v.x; s.y += v.y; s.z += v.z; s.w += v.w;
        den += pden[(size_t)js * NN + i];
    }
    float inv = 1.f / den;
    s.x *= inv; s.y *= inv; s.z *= inv; s.w *= inv;
    *(float4*)&out[(size_t)i * 64 + f4] = s;
}

extern "C" void kernel_launch(void* const* d_in, const int* in_sizes, int n_in,
                              void* d_out, int out_size, void* d_ws, size_t ws_size,
                              hipStream_t stream) {
    const int*   g      = (const int*)d_in[0];
    const float* inputs = (const float*)d_in[1];
    const float* W1     = (const float*)d_in[2];
    const float* a1     = (const float*)d_in[3];
    const float* W2     = (const float*)d_in[4];
    const float* a2     = (const float*)d_in[5];
    float* out = (float*)d_out;
    char* ws = (char*)d_ws;

    size_t off = 0;
    uint64_t* bm   = (uint64_t*)(ws + off); off += (size_t)NN * 64 * 8;              // 2 MB
    unsigned short* Xbf  = (unsigned short*)(ws + off); off += (size_t)NN * KD * 2;  // 4 MB
    unsigned short* W1T  = (unsigned short*)(ws + off); off += (size_t)4 * 128 * KD * 2;
    unsigned short* W2T  = (unsigned short*)(ws + off); off += (size_t)64 * KD * 2;
    unsigned short* WhT1 = (unsigned short*)(ws + off); off += (size_t)4 * 128 * NN * 2; // 4 MB
    unsigned short* WhT2 = (unsigned short*)(ws + off); off += (size_t)64 * NN * 2;      // 0.5 MB
    unsigned short* hbuf = (unsigned short*)(ws + off); off += (size_t)NN * KD * 2;      // 4 MB
    float* s1_1    = (float*)(ws + off);    off += (size_t)4 * NN * 4;
    float* s2_1    = (float*)(ws + off);    off += (size_t)4 * NN * 4;
    float* s1_2    = (float*)(ws + off);    off += (size_t)NN * 4;
    float* s2_2    = (float*)(ws + off);    off += (size_t)NN * 4;
    unsigned int* keys = (unsigned int*)(ws + off); off += 256;   // [0..3] l1, [4] l2
    float* pnum    = (float*)(ws + off);    off += (size_t)8 * NN * 128 * 4;         // 16 MB
    float* pden    = (float*)(ws + off);    off += (size_t)8 * NN * 4;               // 128 KB
    // layer-2 partials alias layer-1's (serial stream, disjoint lifetime)
    float* pnum2 = pnum;
    float* pden2 = pden;

    hipMemsetAsync(keys, 0, 32, stream);
    k_bitmask<<<NN / 4, 256, 0, stream>>>(g, bm);
    k_cast<<<(NN * KD / 4 + 255) / 256, 256, 0, stream>>>(inputs, Xbf, NN * KD / 4);
    k_tc<<<dim3(KD / 64, 2, 4), 256, 0, stream>>>(W1, W1T, KD, 128);
    k_tc<<<dim3(KD / 64, 1, 1), 256, 0, stream>>>(W2, W2T, KD, 64);
    // layer 1
    k_gemm_fused<128><<<dim3(NN / 32, 4), 512, 0, stream>>>(Xbf, W1T, a1, WhT1, s1_1, s2_1, keys);
    // 16 waves/block, 4-way intra-block j-split: grid 256 blocks x 1024 thr = 16 waves/CU
    k_agg3<128, 16, 4><<<dim3(NN / 128, 4, 2), 1024, 0, stream>>>(
        WhT1, s1_1, s2_1, keys, (const unsigned char*)bm, pnum, pden, NN / 128 / 2, 4);
    k_reduce1<<<NN * 128 / 256, 256, 0, stream>>>(pnum, pden, hbuf);
    // layer 2
    k_gemm_fused<64><<<dim3(NN / 32, 1), 512, 0, stream>>>(hbuf, W2T, a2, WhT2, s1_2, s2_2, keys + 4);
    // 8 waves/block, 4-way intra-block j-split: grid 512 blocks x 512 thr = 16 waves/CU
    k_agg3<64, 8, 4><<<dim3(NN / 64, 1, 8), 512, 0, stream>>>(
        WhT2, s1_2, s2_2, keys + 4, (const unsigned char*)bm, pnum2, pden2, NN / 128 / 8, 1);
    k_reduce2<<<NN * 16 / 256, 256, 0, stream>>>(pnum2, pden2, out);
}

// Round 2
// 124.156 us; speedup vs baseline: 1.0518x; 1.0365x over previous
//
#include <hip/hip_runtime.h>
#include <hip/hip_bf16.h>
#include <stdint.h>

#define NN 4096      // nodes
#define KD 512       // input dim of both GEMMs (512 = IN_DIM = HID*HEADS)
#define LOG2E 1.4426950408889634f

typedef __attribute__((ext_vector_type(8))) short short8;
typedef __attribute__((ext_vector_type(4))) float f32x4;

__device__ __forceinline__ float lrelu(float x) { return fmaxf(x, 0.2f * x); }

__device__ __forceinline__ unsigned short f2bf(float f) {
    uint32_t u = __float_as_uint(f);
    u += 0x7fff + ((u >> 16) & 1);           // RNE
    return (unsigned short)(u >> 16);
}

// 2^x via hardware transcendental (scores are pre-scaled by log2e)
__device__ __forceinline__ float exp2_fast(float x) {
    float r; asm("v_exp_f32 %0, %1" : "=v"(r) : "v"(x)); return r;
}

// pack 2 f32 -> 2 bf16 (RNE), lo -> [15:0], hi -> [31:16]
__device__ __forceinline__ uint32_t cvt_pk_bf16(float lo, float hi) {
    uint32_t r; asm("v_cvt_pk_bf16_f32 %0, %1, %2" : "=v"(r) : "v"(lo), "v"(hi)); return r;
}

// async global->LDS, 16B per lane; lds ptr must be wave-uniform base
__device__ __forceinline__ void glds16(const void* g, void* l) {
    __builtin_amdgcn_global_load_lds(
        (const __attribute__((address_space(1))) uint32_t*)g,
        (__attribute__((address_space(3))) uint32_t*)l, 16, 0, 0);
}

// ---------------- bitmask: g[N][N] int32 -> bm[N][64] uint64 ----------------
__global__ void k_bitmask(const int* __restrict__ g, uint64_t* __restrict__ bm) {
    int wave = threadIdx.x >> 6;
    int lane = threadIdx.x & 63;
    int row = blockIdx.x * 4 + wave;
    const int* grow = g + (size_t)row * NN;
    for (int w = 0; w < 64; ++w) {
        int v = grow[w * 64 + lane];
        unsigned long long m = __ballot(v > 0);
        if (lane == 0) bm[(size_t)row * 64 + w] = m;
    }
}

// ---------------- cast f32 -> bf16 (vectorized) ----------------
__global__ void k_cast(const float* __restrict__ x, unsigned short* __restrict__ y, int n4) {
    int i = blockIdx.x * 256 + threadIdx.x;
    if (i < n4) {
        float4 v = ((const float4*)x)[i];
        uint2 o;
        o.x = (uint32_t)f2bf(v.x) | ((uint32_t)f2bf(v.y) << 16);
        o.y = (uint32_t)f2bf(v.z) | ((uint32_t)f2bf(v.w) << 16);
        ((uint2*)y)[i] = o;
    }
}

// ---------------- generic transpose+cast: src f32 [b][R][C] -> dst bf16 [b][C][R] ----------------
__global__ __launch_bounds__(256)
void k_tc(const float* __restrict__ src, unsigned short* __restrict__ dst, int R, int C) {
    __shared__ float tile[64][65];
    int b = blockIdx.z;
    int r0 = blockIdx.x * 64, c0 = blockIdx.y * 64;
    src += (size_t)b * R * C;
    dst += (size_t)b * C * R;
    int t = threadIdx.x;
    #pragma unroll
    for (int s = 0; s < 16; ++s) {
        int idx = t + s * 256;
        int r = idx >> 6, c = idx & 63;
        tile[r][c] = src[(size_t)(r0 + r) * C + c0 + c];
    }
    __syncthreads();
    #pragma unroll
    for (int s = 0; s < 16; ++s) {
        int idx = t + s * 256;
        int r = idx >> 6, c = idx & 63;
        dst[(size_t)(c0 + r) * R + r0 + c] = f2bf(tile[c][r]);
    }
}

// ---------------- fused MFMA GEMM: Wh = A @ W, epilogue writes WhT bf16, s1/s2, smax key ----
// A bf16 [NN][512], WT bf16 [nh][F][512]. BM=32, BK=64, 8 waves (2row x 4col).
// s1/s2/smax are written PRE-SCALED by log2(e) so the aggregation kernel can use v_exp
// (2^x) directly: lrelu commutes with positive scaling.
template <int F>
__global__ __launch_bounds__(512)
void k_gemm_fused(const unsigned short* __restrict__ Abf, const unsigned short* __restrict__ WT,
                  const float* __restrict__ avec,
                  unsigned short* __restrict__ WhT, float* __restrict__ s1g,
                  float* __restrict__ s2g, unsigned int* __restrict__ smaxKey) {
    constexpr int BM = 32, BK = 64;
    constexpr int NCF = F / 64;
    __shared__ unsigned short a_lds[2][BM * BK];
    __shared__ unsigned short b_lds[2][F * BK];
    __shared__ unsigned short t_lds[F * 40];
    __shared__ float sred[BM][2];
    int t = threadIdx.x, lane = t & 63, w = t >> 6;
    int h = blockIdx.y;
    int i0 = blockIdx.x * BM;
    const unsigned short* WTh = WT + (size_t)h * F * KD;
    int r0 = (w >> 2) * 16, c0 = (w & 3) * (F / 4);
    int krow = lane & 15, kgrp = lane >> 4;
    if (t < BM) { sred[t][0] = 0.f; sred[t][1] = 0.f; }
    f32x4 acc[NCF];
    #pragma unroll
    for (int cf = 0; cf < NCF; ++cf) acc[cf] = (f32x4){0.f, 0.f, 0.f, 0.f};

    auto stage = [&](int buf, int kt) {
        int k0 = kt * BK;
        if (w < 4) {            // A tile: 256 chunks
            int c = w * 64 + lane;
            int row = c >> 3, slot = c & 7;
            glds16(Abf + (size_t)(i0 + row) * KD + k0 + ((slot ^ (row & 7)) * 8),
                   &a_lds[buf][(w * 64) * 8]);
        }
        #pragma unroll
        for (int s = 0; s < F / 64; ++s) {   // B tile: 8F chunks
            int c = w * F + s * 64 + lane;
            int row = c >> 3, slot = c & 7;
            glds16(WTh + (size_t)row * KD + k0 + ((slot ^ (row & 7)) * 8),
                   &b_lds[buf][(w * F + s * 64) * 8]);
        }
    };

    stage(0, 0);
    __syncthreads();
    int cur = 0;
    for (int kt = 0; kt < KD / BK; ++kt) {
        int nxt = cur ^ 1;
        if (kt + 1 < KD / BK) stage(nxt, kt + 1);
        #pragma unroll
        for (int ks = 0; ks < 2; ++ks) {
            int koff = ks * 32 + kgrp * 8;
            int arow = r0 + krow;
            short8 av = *(const short8*)((const char*)&a_lds[cur][arow * BK] +
                                         ((koff * 2) ^ ((arow & 7) << 4)));
            #pragma unroll
            for (int cf = 0; cf < NCF; ++cf) {
                int brow = c0 + cf * 16 + krow;
                short8 bv = *(const short8*)((const char*)&b_lds[cur][brow * BK] +
                                             ((koff * 2) ^ ((brow & 7) << 4)));
                acc[cf] = __builtin_amdgcn_mfma_f32_16x16x32_bf16(av, bv, acc[cf], 0, 0, 0);
            }
        }
        __syncthreads();
        cur = nxt;
    }
    // ---- epilogue ----
    // transpose-store acc to t_lds bf16 + score partials
    float p1[4] = {0.f, 0.f, 0.f, 0.f}, p2[4] = {0.f, 0.f, 0.f, 0.f};
    const float* ah = avec + (size_t)h * 2 * F;
    #pragma unroll
    for (int cf = 0; cf < NCF; ++cf) {
        int col = c0 + cf * 16 + krow;
        float aw1 = ah[col], aw2 = ah[F + col];
        #pragma unroll
        for (int r = 0; r < 4; ++r) {
            int row = r0 + kgrp * 4 + r;
            t_lds[col * 40 + row] = f2bf(acc[cf][r]);
            p1[r] += acc[cf][r] * aw1;
            p2[r] += acc[cf][r] * aw2;
        }
    }
    #pragma unroll
    for (int d = 1; d < 16; d <<= 1) {
        #pragma unroll
        for (int r = 0; r < 4; ++r) { p1[r] += __shfl_xor(p1[r], d); p2[r] += __shfl_xor(p2[r], d); }
    }
    if (krow == 0) {
        #pragma unroll
        for (int r = 0; r < 4; ++r) {
            int row = r0 + kgrp * 4 + r;
            atomicAdd(&sred[row][0], p1[r]);
            atomicAdd(&sred[row][1], p2[r]);
        }
    }
    __syncthreads();
    {
        int col = t >> 2, seg = (t & 3) * 8;
        if (col < F) {
            uint4 v = *(const uint4*)&t_lds[col * 40 + seg];
            *(uint4*)&WhT[((size_t)h * F + col) * NN + i0 + seg] = v;
        }
    }
    if (t < BM) {
        s1g[(size_t)h * NN + i0 + t] = sred[t][0] * LOG2E;
        s2g[(size_t)h * NN + i0 + t] = sred[t][1] * LOG2E;
    }
    if (w == 0) {
        float v = (t < BM) ? sred[t][1] * LOG2E : -3.4e38f;
        #pragma unroll
        for (int d = 1; d < 64; d <<= 1) v = fmaxf(v, __shfl_xor(v, d));
        if (lane == 0) {
            uint32_t b = __float_as_uint(v);
            uint32_t key = (b & 0x80000000u) ? ~b : (b | 0x80000000u);
            atomicMax(smaxKey + h, key);
        }
    }
}

// ---------------- register-P MFMA masked-softmax aggregation ----------------
// NW waves; NJH = intra-block j-split (waves per row-group). rg = w/NJH owns
// 32 rows, jh = w%NJH owns a K=32 j-slice of each TJ=NJH*32 tile.
// P computed straight into MFMA A-fragments (no LDS); whT tile tri-buffered, 1 barrier/tile.
// Scores arrive pre-scaled by log2(e): per element t = max(q + c1, 0.2q + c2), p = 2^t.
template <int F, int NW, int NJH>
__global__ __launch_bounds__(NW * 64, 4)
void k_agg3(const unsigned short* __restrict__ WhT, const float* __restrict__ s1v,
            const float* __restrict__ s2v, const unsigned int* __restrict__ smaxKey,
            const unsigned char* __restrict__ bmb,
            float* __restrict__ pnum, float* __restrict__ pden, int njt, int nh) {
    constexpr int TI = (NW / NJH) * 32, TJ = NJH * 32;
    constexpr int NB = F / 16;           // B frags per wave
    constexpr int CPR = TJ / 8;          // 16B staging chunks per whT row
    constexpr int CH_W = F * CPR / NW;   // 16B staging chunks per wave
    constexpr int XF = F + 4;            // padded exchange stride (words) -> no 4-way bank alias
    constexpr int XROWS = TI / 2;        // rows per m-pass
    constexpr size_t ST_BYTES = sizeof(unsigned short) * 3 * F * TJ;
    constexpr size_t XCH_BYTES = sizeof(float) * (size_t)(NJH - 1) * XROWS * XF;
    constexpr size_t SM_BYTES = ST_BYTES > XCH_BYTES ? ST_BYTES : XCH_BYTES;
    __shared__ __align__(16) char smem[SM_BYTES];
    __shared__ float den_sh[NJH][TI];
    auto whT_lds = (unsigned short (*)[F * TJ])smem;
    float* xch = (float*)smem;           // reuse staging LDS for the merge epilogue
    int t = threadIdx.x, l = t & 63, w = t >> 6;
    int h = blockIdx.y, js = blockIdx.z;
    int i0 = blockIdx.x * TI;
    int rg = w / NJH, jh = w % NJH;
    int r0 = rg * 32;
    const unsigned short* WhTh = WhT + (size_t)h * F * NN;
    const float* s2h = s2v + (size_t)h * NN;
    unsigned int kk = smaxKey[h];
    float smax = __uint_as_float((kk & 0x80000000u) ? (kk ^ 0x80000000u) : ~kk);
    int rowA = i0 + r0 + (l & 15);
    int rowB = rowA + 16;
    float s1A = s1v[(size_t)h * NN + rowA];
    float s1B = s1v[(size_t)h * NN + rowB];
    float miA = lrelu(s1A + smax), miB = lrelu(s1B + smax);
    // fold row constants: t = lrelu(s1+q) - mi = max(q + c1, 0.2q + c2)
    float c1A = s1A - miA, c2A = fmaf(0.2f, s1A, -miA);
    float c1B = s1B - miB, c2B = fmaf(0.2f, s1B, -miB);
    int joff = jh * 32 + (l >> 4) * 8;
    int jsbase = js * njt;
    const unsigned char* bmbA = bmb + (size_t)rowA * 512;
    const unsigned char* bmbB = bmb + (size_t)rowB * 512;

    f32x4 acc[2][NB];
    #pragma unroll
    for (int m = 0; m < 2; ++m)
        #pragma unroll
        for (int b = 0; b < NB; ++b) acc[m][b] = (f32x4){0.f, 0.f, 0.f, 0.f};
    float denA = 0.f, denB = 0.f;

    struct SD { float4 q0, q1; unsigned int mA, mB; };
    struct PA { short8 a, b; };

    auto loadSD = [&](int jt) {
        SD s;
        int j0 = (jsbase + jt) * TJ;
        s.q0 = *(const float4*)&s2h[j0 + joff];
        s.q1 = *(const float4*)&s2h[j0 + joff + 4];
        int wb = (jsbase + jt) * CPR + jh * 4 + (l >> 4);
        s.mA = bmbA[wb];
        s.mB = bmbB[wb];
        return s;
    };

    auto computeP = [&](const SD& s) {
        float q[8] = {s.q0.x, s.q0.y, s.q0.z, s.q0.w, s.q1.x, s.q1.y, s.q1.z, s.q1.w};
        float pA[8], pB[8];
        #pragma unroll
        for (int u = 0; u < 8; ++u) {
            float tA = fmaxf(q[u] + c1A, fmaf(0.2f, q[u], c2A));
            float vA = ((s.mA >> u) & 1u) ? exp2_fast(tA) : 0.f;
            denA += vA; pA[u] = vA;
            float tB = fmaxf(q[u] + c1B, fmaf(0.2f, q[u], c2B));
            float vB = ((s.mB >> u) & 1u) ? exp2_fast(tB) : 0.f;
            denB += vB; pB[u] = vB;
        }
        union { uint32_t d[4]; short8 v; } ua, ub;
        #pragma unroll
        for (int j = 0; j < 4; ++j) {
            ua.d[j] = cvt_pk_bf16(pA[2 * j], pA[2 * j + 1]);
            ub.d[j] = cvt_pk_bf16(pB[2 * j], pB[2 * j + 1]);
        }
        PA p; p.a = ua.v; p.b = ub.v;
        return p;
    };

    auto stage = [&](int buf, int jt) {
        int j0 = (jsbase + jt) * TJ;
        #pragma unroll
        for (int s = 0; s < CH_W / 64; ++s) {
            int c = w * CH_W + s * 64 + l;
            int row = c / CPR, slot = c % CPR;
            glds16(WhTh + (size_t)row * NN + j0 + ((slot ^ (row & 7)) * 8),
                   &whT_lds[buf][(w * CH_W + s * 64) * 8]);
        }
    };

    auto domfma = [&](int buf, const PA& pa) {
        #pragma unroll
        for (int b = 0; b < NB; ++b) {
            int brow = b * 16 + (l & 15);
            short8 bv = *(const short8*)((const char*)&whT_lds[buf][brow * TJ] +
                         ((jh * 64 + (l >> 4) * 16) ^ ((brow & 7) << 4)));
            acc[0][b] = __builtin_amdgcn_mfma_f32_16x16x32_bf16(pa.a, bv, acc[0][b], 0, 0, 0);
            acc[1][b] = __builtin_amdgcn_mfma_f32_16x16x32_bf16(pa.b, bv, acc[1][b], 0, 0, 0);
        }
    };

    // prologue
    SD sd_cur = loadSD(0);
    stage(0, 0);
    SD sd_nxt;
    if (njt > 1) sd_nxt = loadSD(1);
    PA pa_cur = computeP(sd_cur);
    __syncthreads();
    int cur = 0, nx1 = 1;
    for (int jt = 0; jt < njt; ++jt) {
        bool more = jt + 1 < njt;
        if (more) stage(nx1, jt + 1);
        SD sd2;
        if (jt + 2 < njt) sd2 = loadSD(jt + 2);
        PA pa_n;
        if (more) pa_n = computeP(sd_nxt);
        __syncthreads();        // tri-buffer: stage target != any in-flight mfma buffer
        domfma(cur, pa_cur);
        pa_cur = pa_n;
        sd_nxt = sd2;
        cur = nx1;
        nx1 = nx1 + 1 == 3 ? 0 : nx1 + 1;
    }

    // den: sum k-groups (lanes sharing l&15)
    denA += __shfl_xor(denA, 16); denA += __shfl_xor(denA, 32);
    denB += __shfl_xor(denB, 16); denB += __shfl_xor(denB, 32);
    if (l < 16) {
        den_sh[jh][r0 + l] = denA;
        den_sh[jh][r0 + 16 + l] = denB;
    }
    __syncthreads();

    // merge jh slices of acc via LDS (two row-passes), write pnum
    float* pnumS = pnum + ((size_t)(js * nh + h) * NN + i0) * F;
    #pragma unroll
    for (int m = 0; m < 2; ++m) {
        if (jh > 0) {
            float* sl = xch + (size_t)(jh - 1) * XROWS * XF;
            #pragma unroll
            for (int b = 0; b < NB; ++b) {
                int col = b * 16 + (l & 15);
                #pragma unroll
                for (int r = 0; r < 4; ++r)
                    sl[(rg * 16 + (l >> 4) * 4 + r) * XF + col] = acc[m][b][r];
            }
        }
        __syncthreads();
        if (jh == 0) {
            #pragma unroll
            for (int b = 0; b < NB; ++b) {
                int col = b * 16 + (l & 15);
                #pragma unroll
                for (int r = 0; r < 4; ++r) {
                    int lrow = rg * 16 + (l >> 4) * 4 + r;
                    int row = r0 + m * 16 + (l >> 4) * 4 + r;
                    float v = acc[m][b][r];
                    #pragma unroll
                    for (int sX = 1; sX < NJH; ++sX)
                        v += xch[((size_t)(sX - 1) * XROWS + lrow) * XF + col];
                    pnumS[(size_t)row * F + col] = v;
                }
            }
        }
        __syncthreads();
    }
    if (t < TI) {
        float d = den_sh[0][t];
        #pragma unroll
        for (int sX = 1; sX < NJH; ++sX) d += den_sh[sX][t];
        pden[(size_t)(js * nh + h) * NN + i0 + t] = d;
    }
}

// ---------------- reduce layer-1 partials -> hbuf bf16 (with ELU) ----------------
__global__ void k_reduce1(const float* __restrict__ pnum, const float* __restrict__ pden,
                          unsigned short* __restrict__ hbuf) {
    int idx = blockIdx.x * 256 + threadIdx.x;   // NN*128 float4s
    int i = idx >> 7;
    int c4 = idx & 127;
    int hh = c4 >> 5, f4 = c4 & 31;
    float4 a = *(const float4*)&pnum[((size_t)hh * NN + i) * 128 + f4 * 4];
    float4 b = *(const float4*)&pnum[((size_t)(4 + hh) * NN + i) * 128 + f4 * 4];
    float den = pden[(size_t)hh * NN + i] + pden[(size_t)(4 + hh) * NN + i];
    float inv = 1.f / den;
    float v[4] = {(a.x + b.x) * inv, (a.y + b.y) * inv, (a.z + b.z) * inv, (a.w + b.w) * inv};
    uint2 o;
    unsigned short e[4];
    #pragma unroll
    for (int u = 0; u < 4; ++u) {
        float x = v[u];
        x = x > 0.f ? x : expm1f(x);
        e[u] = f2bf(x);
    }
    o.x = (uint32_t)e[0] | ((uint32_t)e[1] << 16);
    o.y = (uint32_t)e[2] | ((uint32_t)e[3] << 16);
    *(uint2*)&hbuf[(size_t)i * 512 + c4 * 4] = o;
}

// ---------------- reduce layer-2 partials -> out f32 ----------------
__global__ void k_reduce2(const float* __restrict__ pnum, const float* __restrict__ pden,
                          float* __restrict__ out) {
    int idx = blockIdx.x * 256 + threadIdx.x;   // NN*16 float4s
    int i = idx >> 4;
    int f4 = (idx & 15) * 4;
    float4 s = {0.f, 0.f, 0.f, 0.f};
    float den = 0.f;
    #pragma unroll
    for (int js = 0; js < 8; ++js) {
        float4 v = *(const float4*)&pnum[((size_t)js * NN + i) * 64 + f4];
        s.x += v.x; s.y += v.y; s.z += v.z; s.w += v.w;
        den += pden[(size_t)js * NN + i];
    }
    float inv = 1.f / den;
    s.x *= inv; s.y *= inv; s.z *= inv; s.w *= inv;
    *(float4*)&out[(size_t)i * 64 + f4] = s;
}

extern "C" void kernel_launch(void* const* d_in, const int* in_sizes, int n_in,
                              void* d_out, int out_size, void* d_ws, size_t ws_size,
                              hipStream_t stream) {
    const int*   g      = (const int*)d_in[0];
    const float* inputs = (const float*)d_in[1];
    const float* W1     = (const float*)d_in[2];
    const float* a1     = (const float*)d_in[3];
    const float* W2     = (const float*)d_in[4];
    const float* a2     = (const float*)d_in[5];
    float* out = (float*)d_out;
    char* ws = (char*)d_ws;

    size_t off = 0;
    uint64_t* bm   = (uint64_t*)(ws + off); off += (size_t)NN * 64 * 8;              // 2 MB
    unsigned short* Xbf  = (unsigned short*)(ws + off); off += (size_t)NN * KD * 2;  // 4 MB
    unsigned short* W1T  = (unsigned short*)(ws + off); off += (size_t)4 * 128 * KD * 2;
    unsigned short* W2T  = (unsigned short*)(ws + off); off += (size_t)64 * KD * 2;
    unsigned short* WhT1 = (unsigned short*)(ws + off); off += (size_t)4 * 128 * NN * 2; // 4 MB
    unsigned short* WhT2 = (unsigned short*)(ws + off); off += (size_t)64 * NN * 2;      // 0.5 MB
    unsigned short* hbuf = (unsigned short*)(ws + off); off += (size_t)NN * KD * 2;      // 4 MB
    float* s1_1    = (float*)(ws + off);    off += (size_t)4 * NN * 4;
    float* s2_1    = (float*)(ws + off);    off += (size_t)4 * NN * 4;
    float* s1_2    = (float*)(ws + off);    off += (size_t)NN * 4;
    float* s2_2    = (float*)(ws + off);    off += (size_t)NN * 4;
    unsigned int* keys = (unsigned int*)(ws + off); off += 256;   // [0..3] l1, [4] l2
    float* pnum    = (float*)(ws + off);    off += (size_t)8 * NN * 128 * 4;         // 16 MB
    float* pden    = (float*)(ws + off);    off += (size_t)8 * NN * 4;               // 128 KB
    // layer-2 partials alias layer-1's (serial stream, disjoint lifetime)
    float* pnum2 = pnum;
    float* pden2 = pden;

    hipMemsetAsync(keys, 0, 32, stream);
    k_bitmask<<<NN / 4, 256, 0, stream>>>(g, bm);
    k_cast<<<(NN * KD / 4 + 255) / 256, 256, 0, stream>>>(inputs, Xbf, NN * KD / 4);
    k_tc<<<dim3(KD / 64, 2, 4), 256, 0, stream>>>(W1, W1T, KD, 128);
    k_tc<<<dim3(KD / 64, 1, 1), 256, 0, stream>>>(W2, W2T, KD, 64);
    // layer 1
    k_gemm_fused<128><<<dim3(NN / 32, 4), 512, 0, stream>>>(Xbf, W1T, a1, WhT1, s1_1, s2_1, keys);
    // 16 waves/block, 4-way intra-block j-split: grid 256 blocks x 1024 thr = 16 waves/CU
    k_agg3<128, 16, 4><<<dim3(NN / 128, 4, 2), 1024, 0, stream>>>(
        WhT1, s1_1, s2_1, keys, (const unsigned char*)bm, pnum, pden, NN / 128 / 2, 4);
    k_reduce1<<<NN * 128 / 256, 256, 0, stream>>>(pnum, pden, hbuf);
    // layer 2
    k_gemm_fused<64><<<dim3(NN / 32, 1), 512, 0, stream>>>(hbuf, W2T, a2, WhT2, s1_2, s2_2, keys + 4);
    // 8 waves/block, 4-way intra-block j-split
    k_agg3<64, 8, 4><<<dim3(NN / 64, 1, 8), 512, 0, stream>>>(
        WhT2, s1_2, s2_2, keys + 4, (const unsigned char*)bm, pnum2, pden2, NN / 128 / 8, 1);
    k_reduce2<<<NN * 16 / 256, 256, 0, stream>>>(pnum2, pden2, out);
}